// Round 11
// baseline (1172.871 us; speedup 1.0000x reference)
//
#include <hip/hip_runtime.h>
#include <stdint.h>

#define H 512
#define B_SZ 1024
#define T_WARM 256
#define NSTEPS 64
#define TOTAL_T (T_WARM + NSTEPS)

#define RPB 16          // rows per team
#define HC 128          // cols per block
#define NTEAM 64        // B_SZ / RPB
#define NCG 4           // H / HC
#define NBLK 256        // NTEAM * NCG == CU count, 1 block/CU
#define NTHR 512        // 8 waves

typedef __attribute__((ext_vector_type(8))) short bf16x8;
typedef __attribute__((ext_vector_type(4))) float f32x4;

union u64x2_bf {
    uint64_t u[2];
    bf16x8 v;
};

__device__ __forceinline__ ushort f2bf(float f) {
    uint32_t u = __builtin_bit_cast(uint32_t, f);
    u += 0x7FFFu + ((u >> 16) & 1u);
    return (ushort)(u >> 16);
}
__device__ __forceinline__ float bf2f(ushort h) {
    uint32_t u = ((uint32_t)h) << 16;
    return __builtin_bit_cast(float, u);
}

// Exchange: hi-plane / lo-plane, u32 = bf16(col 2p) | bf16(col 2p+1)<<16, plane[row*256+p].
// A-frags load directly from planes (MFMA-ready order): zero unpack ALU, zero LDS staging.
__global__ void prep_kernel(const float* __restrict__ x,
                            const float* __restrict__ W_hh,
                            const float* __restrict__ b_ih,
                            const float* __restrict__ b_hh,
                            ushort* __restrict__ Wh, ushort* __restrict__ Wl,
                            float* __restrict__ bias, float* __restrict__ xT,
                            uint32_t* __restrict__ Hhi0, uint32_t* __restrict__ Hlo0,
                            uint32_t* __restrict__ flags) {
    int i = blockIdx.x * 512 + threadIdx.x;      // [0, 524288)
    if (i < B_SZ * 256) { Hhi0[i] = 0u; Hlo0[i] = 0u; }   // h(0) = 0
    if (i < 4096) flags[i] = 0u;
    if (i < H * H) {
        float w = W_hh[i];
        ushort hi = f2bf(w);
        float rem = w - bf2f(hi);
        Wh[i] = hi;
        Wl[i] = f2bf(rem);
    }
    if (i < B_SZ * T_WARM) {
        int b = i & (B_SZ - 1), t = i >> 10;
        xT[t * B_SZ + b] = x[b * T_WARM + t];
    }
    if (i < H) bias[i] = b_ih[i] + b_hh[i];
}

__global__ __launch_bounds__(NTHR, 1)
void rnn_kernel(const float* __restrict__ xT,
                const float* __restrict__ W_ih,
                const float* __restrict__ b_fc_p,
                const float* __restrict__ W_fc,
                const ushort* __restrict__ Wh_g,
                const ushort* __restrict__ Wl_g,
                const float* __restrict__ bias_g,
                uint32_t* __restrict__ Hhi0, uint32_t* __restrict__ Hhi1,
                uint32_t* __restrict__ Hlo0, uint32_t* __restrict__ Hlo1,
                uint32_t* __restrict__ flags,
                float* __restrict__ out) {
    __shared__ float pc[8 * 8 * 64 * 4];     // [writer-wave][ctile][lane][4] = 64 KB
    __shared__ float w_fc_s[H];
    __shared__ float w_in_s[HC];
    __shared__ float bias_s[HC];
    __shared__ float ypt[32 * 16];           // y split-K partials [wq][row]
    __shared__ float sx[RPB];
    __shared__ float sy[RPB];

    const int tid = threadIdx.x;
    const int bid = blockIdx.x;
    const int team = bid & (NTEAM - 1);    // members {team,+64,+128,+192}: same bid%8 (XCD)
    const int cg = bid >> 6;               // 0..3
    const int row0 = team * RPB;
    const int col0 = cg * HC;

    w_fc_s[tid] = W_fc[tid];               // NTHR == H
    if (tid < HC) { w_in_s[tid] = W_ih[col0 + tid]; bias_s[tid] = bias_g[col0 + tid]; }
    const float bfc = b_fc_p[0];

    const int lane = tid & 63;
    const int wv = tid >> 6;               // 0..7 = k-slice id AND epilogue col-tile
    const int n = lane & 15, q = lane >> 4;

    // ---- W register-resident, k-sliced: wave wv holds k-cols [wv*64,+64) x all 128 cols ----
    // B-frag (c,ktl): lane(n,q) = W[(col0 + c*16 + n)][wv*64 + ktl*32 + q*8 ..+8]
    bf16x8 Bh[16], Bl[16];
    {
        const int kb = wv * 64 + q * 8;
        #pragma unroll
        for (int c = 0; c < 8; ++c) {
            const ushort* wh = Wh_g + (col0 + c * 16 + n) * H + kb;
            const ushort* wl = Wl_g + (col0 + c * 16 + n) * H + kb;
            Bh[c * 2 + 0] = *(const bf16x8*)(wh);
            Bh[c * 2 + 1] = *(const bf16x8*)(wh + 32);
            Bl[c * 2 + 0] = *(const bf16x8*)(wl);
            Bl[c * 2 + 1] = *(const bf16x8*)(wl + 32);
        }
    }

    uint32_t* myflag = flags + (team * NCG + cg) * 16;
    const uint32_t* pollflag = flags + (team * NCG + (wv >> 1)) * 16;  // ONE producer/wave
    const bool selfw = ((wv >> 1) == cg);

    for (int t = 0; t < TOTAL_T; ++t) {
        float xv = 0.f;
        if (t < T_WARM && tid < RPB) xv = xT[t * B_SZ + row0 + tid];

        // ---- join width 1: poll single producer flag (self slice needs no poll) ----
        if (t > 0 && !selfw) {
            while (__hip_atomic_load(pollflag, __ATOMIC_RELAXED, __HIP_MEMORY_SCOPE_AGENT)
                   < (uint32_t)t)
                __builtin_amdgcn_s_sleep(1);
        }

        // ---- A-frags direct from planes: lane(n,q) row n, k = wv*64 + ktl*32 + q*8 ----
        const uint64_t* ph = (const uint64_t*)((t & 1) ? Hhi1 : Hhi0);
        const uint64_t* pl = (const uint64_t*)((t & 1) ? Hlo1 : Hlo0);
        const int abase = (row0 + n) * 128 + wv * 16 + q * 2;   // u64 idx; ktl stride 8
        u64x2_bf ah[2], al[2];
        #pragma unroll
        for (int ktl = 0; ktl < 2; ++ktl) {
            ah[ktl].u[0] = __hip_atomic_load(ph + abase + ktl * 8 + 0, __ATOMIC_RELAXED, __HIP_MEMORY_SCOPE_AGENT);
            ah[ktl].u[1] = __hip_atomic_load(ph + abase + ktl * 8 + 1, __ATOMIC_RELAXED, __HIP_MEMORY_SCOPE_AGENT);
            al[ktl].u[0] = __hip_atomic_load(pl + abase + ktl * 8 + 0, __ATOMIC_RELAXED, __HIP_MEMORY_SCOPE_AGENT);
            al[ktl].u[1] = __hip_atomic_load(pl + abase + ktl * 8 + 1, __ATOMIC_RELAXED, __HIP_MEMORY_SCOPE_AGENT);
        }

        // ---- 48 MFMA: partial C(16x128) over own k-slice, 8 independent acc chains ----
        f32x4 acc[8];
        #pragma unroll
        for (int c = 0; c < 8; ++c) acc[c] = (f32x4){0.f, 0.f, 0.f, 0.f};
        #pragma unroll
        for (int ktl = 0; ktl < 2; ++ktl) {
            #pragma unroll
            for (int c = 0; c < 8; ++c) {
                acc[c] = __builtin_amdgcn_mfma_f32_16x16x32_bf16(ah[ktl].v, Bh[c * 2 + ktl], acc[c], 0, 0, 0);
                acc[c] = __builtin_amdgcn_mfma_f32_16x16x32_bf16(al[ktl].v, Bh[c * 2 + ktl], acc[c], 0, 0, 0);
                acc[c] = __builtin_amdgcn_mfma_f32_16x16x32_bf16(ah[ktl].v, Bl[c * 2 + ktl], acc[c], 0, 0, 0);
            }
        }

        // ---- publish partials to LDS ----
        #pragma unroll
        for (int c = 0; c < 8; ++c)
            *(f32x4*)(&pc[((wv * 8 + c) * 64 + lane) * 4]) = acc[c];
        if (t < T_WARM && tid < RPB) sx[tid] = xv;
        if (t >= T_WARM) {
            // y split-K partial: lane(n,q) covers row n, its 16 k values
            float yp = 0.f;
            #pragma unroll
            for (int ktl = 0; ktl < 2; ++ktl)
                #pragma unroll
                for (int j = 0; j < 8; ++j) {
                    int k = wv * 64 + ktl * 32 + q * 8 + j;
                    yp += (bf2f((ushort)ah[ktl].v[j]) + bf2f((ushort)al[ktl].v[j])) * w_fc_s[k];
                }
            ypt[(wv * 4 + q) * 16 + n] = yp;
        }
        __syncthreads();   // B1: partials + ypt visible

        if (t >= T_WARM) {
            if (tid < RPB) {
                float s = bfc;
                #pragma unroll
                for (int g = 0; g < 32; ++g) s += ypt[g * 16 + tid];
                sy[tid] = s;
                if (cg == 0) out[(row0 + tid) * NSTEPS + (t - T_WARM)] = s;
            }
            __syncthreads();
        }

        // ---- reduce 8 partials for own col-tile, epilogue, pack, store ----
        f32x4 v = (f32x4){0.f, 0.f, 0.f, 0.f};
        #pragma unroll
        for (int w = 0; w < 8; ++w)
            v += *(const f32x4*)(&pc[((w * 8 + wv) * 64 + lane) * 4]);

        const int jl = wv * 16 + n;
        const float wi = w_in_s[jl], bj = bias_s[jl];
        uint32_t* dsth = ((t & 1) ? Hhi0 : Hhi1);
        uint32_t* dstl = ((t & 1) ? Hlo0 : Hlo1);
        const int pi = (col0 + jl) >> 1;        // col-pair index (col0 even)
        #pragma unroll
        for (int i = 0; i < 4; ++i) {
            int m = q * 4 + i;                  // C/D: row = quad*4+reg, col = lane&15
            float sv = (t < T_WARM) ? sx[m] : sy[m];
            float val = v[i] + sv * wi + bj;
            val = fmaxf(val, 0.f);
            ushort hi = f2bf(val);
            float rem = val - bf2f(hi);
            uint32_t mine = ((uint32_t)hi << 16) | (uint32_t)f2bf(rem);
            uint32_t partner = (uint32_t)__shfl_xor((int)mine, 1);
            int du = (row0 + m) * 256 + pi;
            if ((n & 1) == 0) {                 // even col lane -> hi-plane word
                uint32_t hw = (mine >> 16) | (partner & 0xFFFF0000u);
                __hip_atomic_store(dsth + du, hw, __ATOMIC_RELAXED, __HIP_MEMORY_SCOPE_AGENT);
            } else {                            // odd col lane -> lo-plane word
                uint32_t lw = (partner & 0xFFFFu) | (mine << 16);
                __hip_atomic_store(dstl + du, lw, __ATOMIC_RELAXED, __HIP_MEMORY_SCOPE_AGENT);
            }
        }
        __syncthreads();   // B2: drains all waves' vmem (vmcnt0) before flag publish
        if (tid == 0)
            __hip_atomic_store(myflag, (uint32_t)(t + 1), __ATOMIC_RELAXED, __HIP_MEMORY_SCOPE_AGENT);
    }
}

extern "C" void kernel_launch(void* const* d_in, const int* in_sizes, int n_in,
                              void* d_out, int out_size, void* d_ws, size_t ws_size,
                              hipStream_t stream) {
    const float* x    = (const float*)d_in[0];
    const float* W_ih = (const float*)d_in[1];
    const float* W_hh = (const float*)d_in[2];
    const float* b_ih = (const float*)d_in[3];
    const float* b_hh = (const float*)d_in[4];
    const float* W_fc = (const float*)d_in[5];
    const float* b_fc = (const float*)d_in[6];
    float* out = (float*)d_out;

    // ws carve (bytes): Wh 512K | Wl 512K | bias 4K | xT 1M | Hhi0 1M | Hhi1 1M | Hlo0 1M | Hlo1 1M | flags 16K
    uint8_t* w = (uint8_t*)d_ws;
    ushort*   Wh    = (ushort*)(w);
    ushort*   Wl    = (ushort*)(w + 524288);
    float*    bias  = (float*)(w + 1048576);
    float*    xT    = (float*)(w + 1052672);
    uint32_t* Hhi0  = (uint32_t*)(w + 2101248);
    uint32_t* Hhi1  = (uint32_t*)(w + 3149824);
    uint32_t* Hlo0  = (uint32_t*)(w + 4198400);
    uint32_t* Hlo1  = (uint32_t*)(w + 5246976);
    uint32_t* flags = (uint32_t*)(w + 6295552);

    prep_kernel<<<1024, 512, 0, stream>>>(x, W_hh, b_ih, b_hh, Wh, Wl, bias, xT, Hhi0, Hlo0, flags);
    rnn_kernel<<<NBLK, NTHR, 0, stream>>>(xT, W_ih, b_fc, W_fc, Wh, Wl, bias,
                                          Hhi0, Hhi1, Hlo0, Hlo1, flags, out);
}